// Round 3
// baseline (167906.836 us; speedup 1.0000x reference)
//
#include <hip/hip_runtime.h>
#include <hip/hip_bf16.h>

#define T_STEPS 8192
#define OBS 256
#define HID 2048
#define NOUT 256

// ws layout:
//   [0,     1024)  : flags, 256 x u32 (monotonic step counters)
//   [4096, 20480)  : h_buf, 2 x 2048 f32 (double-buffered hidden state)
//   [65536, +32MB) : hidden, T x HID bf16
#define WS_FLAGS_OFF 0
#define WS_HBUF_OFF 4096
#define WS_HIDDEN_OFF 65536

__global__ void gru_init_kernel(unsigned int* flags, float* h_buf) {
  const int t = threadIdx.x;
  flags[t] = 0u;
  for (int i = t; i < 2 * HID; i += 256) h_buf[i] = 0.f;
}

// Diagnostic: pre-fill hidden with bf16(1.0). If the scan kernel runs, this is
// fully overwritten. If it doesn't, out = bl + rowsum(Wl) (absmax ~5-8),
// distinguishable from "hidden = 0" (absmax 2.4376).
__global__ void hidden_fill_kernel(uint4* hidden) {
  const size_t i = (size_t)blockIdx.x * blockDim.x + threadIdx.x;
  const unsigned p = 0x3F803F80u;  // two bf16(1.0)
  hidden[i] = make_uint4(p, p, p, p);
}

// Persistent scan kernel: 256 blocks x 256 threads, 1 block/CU (grid == #CUs,
// so all blocks are co-resident under a plain launch; the flag protocol below
// provides the device-wide step barrier — no grid.sync needed).
// Block w owns hidden units i = w*8 .. w*8+7, i.e. rows {i, H+i, 2H+i} of
// wh/wi/b. All 24 wh rows (fp32) + 24 wi rows live in VGPRs.
__global__ __launch_bounds__(256, 1) void gru_scan_kernel(
    const float* __restrict__ ys, const float* __restrict__ wi,
    const float* __restrict__ wh, const float* __restrict__ b,
    const float* __restrict__ bn, __hip_bfloat16* __restrict__ hidden,
    float* h_buf, unsigned int* flags) {
  const int w = blockIdx.x;
  const int tid = threadIdx.x;
  const int wave = tid >> 6;
  const int lane = tid & 63;

  __shared__ float h_lds[HID];
  __shared__ float x_lds[2 * OBS];
  __shared__ float dot_wh[24];
  __shared__ float dot_wi[24];

  // ---- one-time: stage weights into registers (coalesced float4 loads) ----
  float4 whr[6][8];
  float4 wir[6][2];
#pragma unroll
  for (int r = 0; r < 6; ++r) {
    const int lr = wave * 6 + r;   // 0..23
    const int g = lr >> 3;         // gate 0=r,1=z,2=n
    const int e = lr & 7;
    const size_t R = (size_t)(g * HID + w * 8 + e);
#pragma unroll
    for (int m = 0; m < 8; ++m)
      whr[r][m] =
          *reinterpret_cast<const float4*>(wh + R * HID + m * 256 + lane * 4);
#pragma unroll
    for (int p = 0; p < 2; ++p)
      wir[r][p] =
          *reinterpret_cast<const float4*>(wi + R * 512 + p * 256 + lane * 4);
  }
  const int i8 = w * 8 + (tid & 7);
  const float b_r = b[i8];
  const float b_z = b[HID + i8];
  const float b_n = b[2 * HID + i8];
  const float bn_v = bn[i8];

#pragma unroll 1
  for (int s = 0; s < T_STEPS; ++s) {
    const float* hcur = h_buf + (s & 1) * HID;
    float* hnext = h_buf + ((s + 1) & 1) * HID;

    // ---- wait until every block has published step s ----
    // Thread tid polls block tid's flag; the __syncthreads() below makes this
    // a wait on ALL 256 blocks before ANY thread reads h.
    {
      const unsigned int target = (unsigned int)s;
      while (__hip_atomic_load(&flags[tid], __ATOMIC_RELAXED,
                               __HIP_MEMORY_SCOPE_AGENT) < target) {
        __builtin_amdgcn_s_sleep(1);
      }
    }
    __builtin_amdgcn_fence(__ATOMIC_ACQUIRE, "agent");
    __syncthreads();  // collectively confirm all 256 flags

    // ---- stage h (agent-scope loads: bypass stale per-XCD caches) and x ----
#pragma unroll
    for (int u = 0; u < 8; ++u) {
      const int j = u * 256 + tid;
      h_lds[j] = __hip_atomic_load(hcur + j, __ATOMIC_RELAXED,
                                   __HIP_MEMORY_SCOPE_AGENT);
    }
    {
      const float y = ys[(size_t)s * OBS + tid];
      const bool good = (y == y);  // !isnan
      x_lds[tid] = good ? y : 0.f;
      x_lds[OBS + tid] = good ? 1.f : 0.f;
    }
    __syncthreads();

    float4 hreg[8], xreg[2];
#pragma unroll
    for (int m = 0; m < 8; ++m)
      hreg[m] = *reinterpret_cast<const float4*>(&h_lds[m * 256 + lane * 4]);
#pragma unroll
    for (int p = 0; p < 2; ++p)
      xreg[p] = *reinterpret_cast<const float4*>(&x_lds[p * 256 + lane * 4]);

    // ---- 6 rows per wave: fp32 dot products + wave reduce ----
#pragma unroll
    for (int r = 0; r < 6; ++r) {
      float aw = 0.f, ai = 0.f;
#pragma unroll
      for (int m = 0; m < 8; ++m) {
        aw += whr[r][m].x * hreg[m].x;
        aw += whr[r][m].y * hreg[m].y;
        aw += whr[r][m].z * hreg[m].z;
        aw += whr[r][m].w * hreg[m].w;
      }
#pragma unroll
      for (int p = 0; p < 2; ++p) {
        ai += wir[r][p].x * xreg[p].x;
        ai += wir[r][p].y * xreg[p].y;
        ai += wir[r][p].z * xreg[p].z;
        ai += wir[r][p].w * xreg[p].w;
      }
#pragma unroll
      for (int off = 32; off > 0; off >>= 1) {
        aw += __shfl_xor(aw, off, 64);
        ai += __shfl_xor(ai, off, 64);
      }
      if (lane == 0) {
        dot_wh[wave * 6 + r] = aw;
        dot_wi[wave * 6 + r] = ai;
      }
    }
    __syncthreads();

    // ---- gate math + publish (8 threads) ----
    if (tid < 8) {
      const int i = w * 8 + tid;
      const float rpre = dot_wi[tid] + b_r + dot_wh[tid];
      const float zpre = dot_wi[8 + tid] + b_z + dot_wh[8 + tid];
      const float rg = 1.f / (1.f + expf(-rpre));
      const float zg = 1.f / (1.f + expf(-zpre));
      const float ng =
          tanhf(dot_wi[16 + tid] + b_n + rg * (dot_wh[16 + tid] + bn_v));
      const float hold = h_lds[i];
      const float hnew = ng + zg * (hold - ng);
      __hip_atomic_store(hnext + i, hnew, __ATOMIC_RELAXED,
                         __HIP_MEMORY_SCOPE_AGENT);
      hidden[(size_t)s * HID + i] = __float2bfloat16(hnew);
      __builtin_amdgcn_fence(__ATOMIC_RELEASE, "agent");
    }
    __syncthreads();  // h stores happen-before the flag release-store below
    if (tid == 0)
      __hip_atomic_store(&flags[w], (unsigned int)(s + 1), __ATOMIC_RELEASE,
                         __HIP_MEMORY_SCOPE_AGENT);
  }
}

// out[t][o] = bl[o] + sum_k hidden[t][k] * Wl[o][k]
// 64x64 tile, 256 threads, 4x4 micro-tile, BK=16.
__global__ __launch_bounds__(256) void out_gemm_kernel(
    const __hip_bfloat16* __restrict__ hidden, const float* __restrict__ Wl,
    const float* __restrict__ bl, float* __restrict__ out) {
  __shared__ float As[16][68];
  __shared__ float Bs[16][68];
  const int tid = threadIdx.x;
  const int bt = blockIdx.x * 64;
  const int bo = blockIdx.y * 64;
  const int tx = tid & 15;
  const int ty = tid >> 4;
  const int tA = tid >> 2;          // 0..63
  const int kq = (tid & 3) << 2;    // 0,4,8,12
  const unsigned short* hidu = reinterpret_cast<const unsigned short*>(hidden);

  float acc[4][4];
#pragma unroll
  for (int i = 0; i < 4; ++i)
#pragma unroll
    for (int j = 0; j < 4; ++j) acc[i][j] = 0.f;

  for (int k0 = 0; k0 < HID; k0 += 16) {
    const ushort4 av = *reinterpret_cast<const ushort4*>(
        hidu + (size_t)(bt + tA) * HID + k0 + kq);
    As[kq + 0][tA] = __uint_as_float((unsigned)av.x << 16);
    As[kq + 1][tA] = __uint_as_float((unsigned)av.y << 16);
    As[kq + 2][tA] = __uint_as_float((unsigned)av.z << 16);
    As[kq + 3][tA] = __uint_as_float((unsigned)av.w << 16);
    const float4 bv = *reinterpret_cast<const float4*>(
        Wl + (size_t)(bo + tA) * HID + k0 + kq);
    Bs[kq + 0][tA] = bv.x;
    Bs[kq + 1][tA] = bv.y;
    Bs[kq + 2][tA] = bv.z;
    Bs[kq + 3][tA] = bv.w;
    __syncthreads();
#pragma unroll
    for (int k = 0; k < 16; ++k) {
      const float4 a = *reinterpret_cast<const float4*>(&As[k][ty << 2]);
      const float4 bq = *reinterpret_cast<const float4*>(&Bs[k][tx << 2]);
      const float a4[4] = {a.x, a.y, a.z, a.w};
      const float b4[4] = {bq.x, bq.y, bq.z, bq.w};
#pragma unroll
      for (int i = 0; i < 4; ++i)
#pragma unroll
        for (int j = 0; j < 4; ++j) acc[i][j] += a4[i] * b4[j];
    }
    __syncthreads();
  }
#pragma unroll
  for (int i = 0; i < 4; ++i) {
    const int t = bt + (ty << 2) + i;
#pragma unroll
    for (int j = 0; j < 4; ++j) {
      const int o = bo + (tx << 2) + j;
      out[(size_t)t * NOUT + o] = acc[i][j] + bl[o];
    }
  }
}

extern "C" void kernel_launch(void* const* d_in, const int* in_sizes, int n_in,
                              void* d_out, int out_size, void* d_ws,
                              size_t ws_size, hipStream_t stream) {
  (void)in_sizes;
  (void)n_in;
  (void)out_size;
  (void)ws_size;
  // setup_inputs order: ts, ys, wi, wh, b, bn, Wl, bl (all f32)
  const float* ys = (const float*)d_in[1];
  const float* wi = (const float*)d_in[2];
  const float* wh = (const float*)d_in[3];
  const float* b = (const float*)d_in[4];
  const float* bn = (const float*)d_in[5];
  const float* Wl = (const float*)d_in[6];
  const float* bl = (const float*)d_in[7];
  float* out = (float*)d_out;

  unsigned int* flags = (unsigned int*)((char*)d_ws + WS_FLAGS_OFF);
  float* h_buf = (float*)((char*)d_ws + WS_HBUF_OFF);
  __hip_bfloat16* hidden = (__hip_bfloat16*)((char*)d_ws + WS_HIDDEN_OFF);

  gru_init_kernel<<<1, 256, 0, stream>>>(flags, h_buf);
  // Diagnostic fill: T*HID bf16 = 2,097,152 uint4s.
  hidden_fill_kernel<<<8192, 256, 0, stream>>>((uint4*)hidden);

  // Plain launch (NOT hipLaunchCooperativeKernel — that path never executed in
  // this harness). grid == 256 == #CUs with 1 block/CU => co-resident.
  gru_scan_kernel<<<dim3(256), dim3(256), 0, stream>>>(ys, wi, wh, b, bn,
                                                       hidden, h_buf, flags);

  out_gemm_kernel<<<dim3(T_STEPS / 64, NOUT / 64), 256, 0, stream>>>(
      hidden, Wl, bl, out);
}

// Round 4
// 38610.504 us; speedup vs baseline: 4.3487x; 4.3487x over previous
//
#include <hip/hip_runtime.h>
#include <hip/hip_bf16.h>

#define T_STEPS 8192
#define OBS 256
#define HID 2048
#define NOUT 256

// ws layout:
//   [4096, 36864)  : h_tag, 2 x 2048 x u64  {tag:u32 (hi), f32 bits (lo)}
//   [65536, +32MB) : hidden, T x HID bf16
#define WS_HBUF_OFF 4096
#define WS_HIDDEN_OFF 65536

typedef unsigned long long u64;

// Zero both tagged-h buffers: tag=0, value=0.0f. Reader of step 0 wants
// tag==0 => immediately satisfied with h0 = 0.
__global__ void gru_init_kernel(u64* h_tag) {
  const int t = blockIdx.x * blockDim.x + threadIdx.x;
  h_tag[t] = 0ull;  // 2*HID = 4096 entries
}

// Persistent scan: 256 blocks x 256 threads, 1 block/CU (grid == #CUs => all
// co-resident under a plain launch). Block w owns hidden units w*8..w*8+7,
// i.e. rows {i, H+i, 2H+i} of wh/wi/b, held as fp32 in VGPRs.
//
// Cross-block exchange uses SELF-VALIDATING tagged values: one atomic u64 per
// h element = {step-tag, f32 value}. No fences anywhere in the loop (an
// agent-scope fence on gfx950 costs an L2 invalidate/writeback; that was
// ~23 us/step in round 3). Relaxed agent-scope loads/stores only.
__global__ __launch_bounds__(256, 1) void gru_scan_kernel(
    const float* __restrict__ ys, const float* __restrict__ wi,
    const float* __restrict__ wh, const float* __restrict__ b,
    const float* __restrict__ bn, __hip_bfloat16* __restrict__ hidden,
    u64* h_tag) {
  const int w = blockIdx.x;
  const int tid = threadIdx.x;
  const int wave = tid >> 6;
  const int lane = tid & 63;

  __shared__ float h_lds[HID];
  __shared__ float x_lds[2 * OBS];
  __shared__ float dot_wh[24];
  __shared__ float dot_wi[24];

  // ---- one-time: stage weights into registers (coalesced float4 loads) ----
  float4 whr[6][8];
  float4 wir[6][2];
#pragma unroll
  for (int r = 0; r < 6; ++r) {
    const int lr = wave * 6 + r;   // 0..23
    const int g = lr >> 3;         // gate 0=r,1=z,2=n
    const int e = lr & 7;
    const size_t R = (size_t)(g * HID + w * 8 + e);
#pragma unroll
    for (int m = 0; m < 8; ++m)
      whr[r][m] =
          *reinterpret_cast<const float4*>(wh + R * HID + m * 256 + lane * 4);
#pragma unroll
    for (int p = 0; p < 2; ++p)
      wir[r][p] =
          *reinterpret_cast<const float4*>(wi + R * 512 + p * 256 + lane * 4);
  }
  const int i8 = w * 8 + (tid & 7);
  const float b_r = b[i8];
  const float b_z = b[HID + i8];
  const float b_n = b[2 * HID + i8];
  const float bn_v = bn[i8];

#pragma unroll 1
  for (int s = 0; s < T_STEPS; ++s) {
    const u64* hp = h_tag + (s & 1) * HID;
    u64* hp_next = h_tag + ((s + 1) & 1) * HID;
    const unsigned tag = (unsigned)s;

    // ---- ys load first (independent; overlaps with the polls below) ----
    const float y = ys[(size_t)s * OBS + tid];

    // ---- poll tagged h: 8 slots/thread, batched retries ----
    u64 v[8];
#pragma unroll
    for (int u = 0; u < 8; ++u)
      v[u] = __hip_atomic_load(hp + u * 256 + tid, __ATOMIC_RELAXED,
                               __HIP_MEMORY_SCOPE_AGENT);
    while (true) {
      bool ok = true;
#pragma unroll
      for (int u = 0; u < 8; ++u) ok &= ((unsigned)(v[u] >> 32) == tag);
      if (ok) break;
      __builtin_amdgcn_s_sleep(2);  // throttle poll traffic to L3
#pragma unroll
      for (int u = 0; u < 8; ++u)
        v[u] = __hip_atomic_load(hp + u * 256 + tid, __ATOMIC_RELAXED,
                                 __HIP_MEMORY_SCOPE_AGENT);
    }

    // ---- stage h and x into LDS ----
#pragma unroll
    for (int u = 0; u < 8; ++u)
      h_lds[u * 256 + tid] = __uint_as_float((unsigned)v[u]);
    {
      const bool good = (y == y);  // !isnan
      x_lds[tid] = good ? y : 0.f;
      x_lds[OBS + tid] = good ? 1.f : 0.f;
    }
    __syncthreads();

    float4 hreg[8], xreg[2];
#pragma unroll
    for (int m = 0; m < 8; ++m)
      hreg[m] = *reinterpret_cast<const float4*>(&h_lds[m * 256 + lane * 4]);
#pragma unroll
    for (int p = 0; p < 2; ++p)
      xreg[p] = *reinterpret_cast<const float4*>(&x_lds[p * 256 + lane * 4]);

    // ---- 6 rows per wave: fp32 dot products + wave reduce ----
#pragma unroll
    for (int r = 0; r < 6; ++r) {
      float aw = 0.f, ai = 0.f;
#pragma unroll
      for (int m = 0; m < 8; ++m) {
        aw += whr[r][m].x * hreg[m].x;
        aw += whr[r][m].y * hreg[m].y;
        aw += whr[r][m].z * hreg[m].z;
        aw += whr[r][m].w * hreg[m].w;
      }
#pragma unroll
      for (int p = 0; p < 2; ++p) {
        ai += wir[r][p].x * xreg[p].x;
        ai += wir[r][p].y * xreg[p].y;
        ai += wir[r][p].z * xreg[p].z;
        ai += wir[r][p].w * xreg[p].w;
      }
#pragma unroll
      for (int off = 32; off > 0; off >>= 1) {
        aw += __shfl_xor(aw, off, 64);
        ai += __shfl_xor(ai, off, 64);
      }
      if (lane == 0) {
        dot_wh[wave * 6 + r] = aw;
        dot_wi[wave * 6 + r] = ai;
      }
    }
    __syncthreads();

    // ---- gate math + tagged publish (8 threads; no fence needed) ----
    if (tid < 8) {
      const int i = w * 8 + tid;
      const float rpre = dot_wi[tid] + b_r + dot_wh[tid];
      const float zpre = dot_wi[8 + tid] + b_z + dot_wh[8 + tid];
      const float rg = 1.f / (1.f + expf(-rpre));
      const float zg = 1.f / (1.f + expf(-zpre));
      const float ng =
          tanhf(dot_wi[16 + tid] + b_n + rg * (dot_wh[16 + tid] + bn_v));
      const float hold = h_lds[i];
      const float hnew = ng + zg * (hold - ng);
      const u64 pv =
          ((u64)(unsigned)(s + 1) << 32) | (u64)(unsigned)__float_as_uint(hnew);
      __hip_atomic_store(hp_next + i, pv, __ATOMIC_RELAXED,
                         __HIP_MEMORY_SCOPE_AGENT);
      hidden[(size_t)s * HID + i] = __float2bfloat16(hnew);
    }
    __syncthreads();  // protect h_lds/dot_lds against next iteration's writes
  }
}

// out[t][o] = bl[o] + sum_k hidden[t][k] * Wl[o][k]
// 64x64 tile, 256 threads, 4x4 micro-tile, BK=16.
__global__ __launch_bounds__(256) void out_gemm_kernel(
    const __hip_bfloat16* __restrict__ hidden, const float* __restrict__ Wl,
    const float* __restrict__ bl, float* __restrict__ out) {
  __shared__ float As[16][68];
  __shared__ float Bs[16][68];
  const int tid = threadIdx.x;
  const int bt = blockIdx.x * 64;
  const int bo = blockIdx.y * 64;
  const int tx = tid & 15;
  const int ty = tid >> 4;
  const int tA = tid >> 2;          // 0..63
  const int kq = (tid & 3) << 2;    // 0,4,8,12
  const unsigned short* hidu = reinterpret_cast<const unsigned short*>(hidden);

  float acc[4][4];
#pragma unroll
  for (int i = 0; i < 4; ++i)
#pragma unroll
    for (int j = 0; j < 4; ++j) acc[i][j] = 0.f;

  for (int k0 = 0; k0 < HID; k0 += 16) {
    const ushort4 av = *reinterpret_cast<const ushort4*>(
        hidu + (size_t)(bt + tA) * HID + k0 + kq);
    As[kq + 0][tA] = __uint_as_float((unsigned)av.x << 16);
    As[kq + 1][tA] = __uint_as_float((unsigned)av.y << 16);
    As[kq + 2][tA] = __uint_as_float((unsigned)av.z << 16);
    As[kq + 3][tA] = __uint_as_float((unsigned)av.w << 16);
    const float4 bv = *reinterpret_cast<const float4*>(
        Wl + (size_t)(bo + tA) * HID + k0 + kq);
    Bs[kq + 0][tA] = bv.x;
    Bs[kq + 1][tA] = bv.y;
    Bs[kq + 2][tA] = bv.z;
    Bs[kq + 3][tA] = bv.w;
    __syncthreads();
#pragma unroll
    for (int k = 0; k < 16; ++k) {
      const float4 a = *reinterpret_cast<const float4*>(&As[k][ty << 2]);
      const float4 bq = *reinterpret_cast<const float4*>(&Bs[k][tx << 2]);
      const float a4[4] = {a.x, a.y, a.z, a.w};
      const float b4[4] = {bq.x, bq.y, bq.z, bq.w};
#pragma unroll
      for (int i = 0; i < 4; ++i)
#pragma unroll
        for (int j = 0; j < 4; ++j) acc[i][j] += a4[i] * b4[j];
    }
    __syncthreads();
  }
#pragma unroll
  for (int i = 0; i < 4; ++i) {
    const int t = bt + (ty << 2) + i;
#pragma unroll
    for (int j = 0; j < 4; ++j) {
      const int o = bo + (tx << 2) + j;
      out[(size_t)t * NOUT + o] = acc[i][j] + bl[o];
    }
  }
}

extern "C" void kernel_launch(void* const* d_in, const int* in_sizes, int n_in,
                              void* d_out, int out_size, void* d_ws,
                              size_t ws_size, hipStream_t stream) {
  (void)in_sizes;
  (void)n_in;
  (void)out_size;
  (void)ws_size;
  // setup_inputs order: ts, ys, wi, wh, b, bn, Wl, bl (all f32)
  const float* ys = (const float*)d_in[1];
  const float* wi = (const float*)d_in[2];
  const float* wh = (const float*)d_in[3];
  const float* b = (const float*)d_in[4];
  const float* bn = (const float*)d_in[5];
  const float* Wl = (const float*)d_in[6];
  const float* bl = (const float*)d_in[7];
  float* out = (float*)d_out;

  u64* h_tag = (u64*)((char*)d_ws + WS_HBUF_OFF);
  __hip_bfloat16* hidden = (__hip_bfloat16*)((char*)d_ws + WS_HIDDEN_OFF);

  gru_init_kernel<<<16, 256, 0, stream>>>(h_tag);

  gru_scan_kernel<<<dim3(256), dim3(256), 0, stream>>>(ys, wi, wh, b, bn,
                                                       hidden, h_tag);

  out_gemm_kernel<<<dim3(T_STEPS / 64, NOUT / 64), 256, 0, stream>>>(
      hidden, Wl, bl, out);
}

// Round 6
// 31718.253 us; speedup vs baseline: 5.2937x; 1.2173x over previous
//
#include <hip/hip_runtime.h>
#include <hip/hip_bf16.h>

#define T_STEPS 8192
#define OBS 256
#define HID 2048
#define NOUT 256

typedef unsigned long long u64;
typedef _Float16 half2v __attribute__((ext_vector_type(2)));
typedef __fp16 fp16x2 __attribute__((ext_vector_type(2)));

// ws layout:
//   [4096, 36864)  : h_tag, 2 x 2048 x u64  {tag:u32 (hi), f32 bits (lo)}
//   [65536, +32MB) : hidden, T x HID bf16
#define WS_HBUF_OFF 4096
#define WS_HIDDEN_OFF 65536

__global__ void gru_init_kernel(u64* h_tag) {
  const int t = blockIdx.x * blockDim.x + threadIdx.x;
  h_tag[t] = 0ull;  // 2*HID entries: tag=0, value=0.0f
}

__device__ __forceinline__ half2v bc_h2(unsigned u) {
  union { unsigned u; half2v h; } c;
  c.u = u;
  return c.h;
}
__device__ __forceinline__ unsigned pk_rn(float lo, float hi) {
  union { half2v h; unsigned u; } c;
  c.h[0] = (_Float16)lo;  // RNE
  c.h[1] = (_Float16)hi;
  return c.u;
}
__device__ __forceinline__ unsigned pk_rtz(float lo, float hi) {
  union { fp16x2 h; unsigned u; } c;  // fp16x2 == builtin's return type
  c.h = __builtin_amdgcn_cvt_pkrtz(lo, hi);
  return c.u;
}
__device__ __forceinline__ float fdot2f(unsigned a, unsigned b, float c) {
#if __has_builtin(__builtin_amdgcn_fdot2)
  return __builtin_amdgcn_fdot2(bc_h2(a), bc_h2(b), c, false);
#else
  const half2v ha = bc_h2(a), hb = bc_h2(b);
  return c + (float)ha[0] * (float)hb[0] + (float)ha[1] * (float)hb[1];
#endif
}

// Persistent scan: 256 blocks x 256 threads, 1 block/CU. Block w owns hidden
// units w*8..w*8+7; wave v owns units w*8+2v, +2v+1 (rows {i,H+i,2H+i} each),
// held as PACKED FP16 in VGPRs (120 regs) — asm-pinned so the compiler cannot
// re-load them per step (round-4 failure: VGPR_Count=160 proved weights were
// re-fetched from L2/L3 every step). Dot via v_dot2_f32_f16 (f32 accum).
// Cross-block exchange: self-validating tagged u64 {step-tag, f32 value},
// relaxed agent-scope atomics, no fences. One __syncthreads per step
// (h/x LDS double-buffered; per-wave gate math needs no cross-wave sync).
__global__ __launch_bounds__(256, 1) void gru_scan_kernel(
    const float* __restrict__ ys, const float* __restrict__ wi,
    const float* __restrict__ wh, const float* __restrict__ b,
    const float* __restrict__ bn, __hip_bfloat16* __restrict__ hidden,
    u64* h_tag) {
  const int w = blockIdx.x;
  const int tid = threadIdx.x;
  const int wave = tid >> 6;
  const int lane = tid & 63;

  __shared__ float h_lds[2][HID];
  __shared__ float x_lds[2][2 * OBS];

  // ---- one-time: stage 6 rows/wave of wh,wi as packed fp16 in VGPRs ----
  // Row r = g*2+e (g=gate 0..2, e=unit 0..1): global row g*HID + w*8 + 2*wave + e.
  // Lane covers elements m*256 + lane*4 + {0..3} of each row (m chunks).
  unsigned whp[6][16];
  unsigned wip[6][4];
#pragma unroll
  for (int r = 0; r < 6; ++r) {
    const int g = r >> 1, e = r & 1;
    const size_t R = (size_t)(g * HID + w * 8 + 2 * wave + e);
#pragma unroll
    for (int m = 0; m < 8; ++m) {
      const float4 q =
          *reinterpret_cast<const float4*>(wh + R * HID + m * 256 + lane * 4);
      whp[r][2 * m] = pk_rn(q.x, q.y);
      whp[r][2 * m + 1] = pk_rn(q.z, q.w);
    }
#pragma unroll
    for (int p = 0; p < 2; ++p) {
      const float4 q =
          *reinterpret_cast<const float4*>(wi + R * 512 + p * 256 + lane * 4);
      wip[r][2 * p] = pk_rn(q.x, q.y);
      wip[r][2 * p + 1] = pk_rn(q.z, q.w);
    }
  }
  // Sever the values from their loads: compiler must keep them in VGPRs.
#pragma unroll
  for (int r = 0; r < 6; ++r) {
#pragma unroll
    for (int m = 0; m < 16; ++m) asm volatile("" : "+v"(whp[r][m]));
#pragma unroll
    for (int p = 0; p < 4; ++p) asm volatile("" : "+v"(wip[r][p]));
  }

  // Per-lane gate constants for this wave's two units (lane&1 selects unit).
  const int iu = w * 8 + 2 * wave + (lane & 1);
  const float b_r = b[iu];
  const float b_z = b[HID + iu];
  const float b_n = b[2 * HID + iu];
  const float bn_v = bn[iu];

#pragma unroll 1
  for (int s = 0; s < T_STEPS; ++s) {
    const int buf = s & 1;
    const u64* hp = h_tag + buf * HID;
    u64* hp_next = h_tag + (buf ^ 1) * HID;
    const unsigned tag = (unsigned)s;

    // independent ys load overlaps the polls
    const float y = ys[(size_t)s * OBS + tid];

    // ---- poll tagged h: 8 slots/thread, re-load ONLY stale slots ----
    u64 v[8];
    unsigned pend = 0xFFu;
#pragma unroll
    for (int u = 0; u < 8; ++u) {
      v[u] = __hip_atomic_load(hp + u * 256 + tid, __ATOMIC_RELAXED,
                               __HIP_MEMORY_SCOPE_AGENT);
      if ((unsigned)(v[u] >> 32) == tag) pend &= ~(1u << u);
    }
    while (pend) {
      __builtin_amdgcn_s_sleep(1);
#pragma unroll
      for (int u = 0; u < 8; ++u) {
        if (pend & (1u << u)) {
          v[u] = __hip_atomic_load(hp + u * 256 + tid, __ATOMIC_RELAXED,
                                   __HIP_MEMORY_SCOPE_AGENT);
          if ((unsigned)(v[u] >> 32) == tag) pend &= ~(1u << u);
        }
      }
    }

    // ---- stage h and x into this step's LDS buffer ----
#pragma unroll
    for (int u = 0; u < 8; ++u)
      h_lds[buf][u * 256 + tid] = __uint_as_float((unsigned)v[u]);
    {
      const bool good = (y == y);  // !isnan
      x_lds[buf][tid] = good ? y : 0.f;
      x_lds[buf][OBS + tid] = good ? 1.f : 0.f;
    }
    __syncthreads();  // the ONLY barrier per step

    // ---- fragments: read f32, pack to fp16 pairs (RTZ, 1 instr/pair) ----
    unsigned hq[16], xq[4];
#pragma unroll
    for (int m = 0; m < 8; ++m) {
      const float4 q =
          *reinterpret_cast<const float4*>(&h_lds[buf][m * 256 + lane * 4]);
      hq[2 * m] = pk_rtz(q.x, q.y);
      hq[2 * m + 1] = pk_rtz(q.z, q.w);
    }
#pragma unroll
    for (int p = 0; p < 2; ++p) {
      const float4 q =
          *reinterpret_cast<const float4*>(&x_lds[buf][p * 256 + lane * 4]);
      xq[2 * p] = pk_rtz(q.x, q.y);
      xq[2 * p + 1] = pk_rtz(q.z, q.w);
    }

    // ---- dots. r/z rows: wh·h + wi·x combined (one reduce each).
    //      n rows: wh·h and wi·x kept separate (reset gate scales only hg).
    float red[8];
#pragma unroll
    for (int r = 0; r < 4; ++r) {  // rows 0,1 = reset; 2,3 = update
      float a = 0.f;
#pragma unroll
      for (int m = 0; m < 16; ++m) a = fdot2f(whp[r][m], hq[m], a);
#pragma unroll
      for (int p = 0; p < 4; ++p) a = fdot2f(wip[r][p], xq[p], a);
#pragma unroll
      for (int off = 32; off > 0; off >>= 1) a += __shfl_xor(a, off, 64);
      red[r] = a;
    }
#pragma unroll
    for (int r = 4; r < 6; ++r) {  // rows 4,5 = candidate (n)
      float aw = 0.f, ai = 0.f;
#pragma unroll
      for (int m = 0; m < 16; ++m) aw = fdot2f(whp[r][m], hq[m], aw);
#pragma unroll
      for (int p = 0; p < 4; ++p) ai = fdot2f(wip[r][p], xq[p], ai);
#pragma unroll
      for (int off = 32; off > 0; off >>= 1) {
        aw += __shfl_xor(aw, off, 64);
        ai += __shfl_xor(ai, off, 64);
      }
      red[r] = aw;      // wh·h part
      red[r + 2] = ai;  // wi·x part
    }

    // ---- per-wave gate math + tagged publish (lanes 0,1; no extra sync) ----
    if (lane < 2) {
      const int uu = lane;
      const float d_r = uu ? red[1] : red[0];
      const float d_z = uu ? red[3] : red[2];
      const float d_hn = uu ? red[5] : red[4];
      const float d_in = uu ? red[7] : red[6];
      const float rg = 1.f / (1.f + expf(-(d_r + b_r)));
      const float zg = 1.f / (1.f + expf(-(d_z + b_z)));
      const float ng = tanhf(d_in + b_n + rg * (d_hn + bn_v));
      const int i = w * 8 + 2 * wave + uu;
      const float hold = h_lds[buf][i];
      const float hnew = ng + zg * (hold - ng);
      const u64 pv = ((u64)(tag + 1) << 32) | (u64)__float_as_uint(hnew);
      __hip_atomic_store(hp_next + i, pv, __ATOMIC_RELAXED,
                         __HIP_MEMORY_SCOPE_AGENT);
      hidden[(size_t)s * HID + i] = __float2bfloat16(hnew);  // off crit. path
    }
    // no end-of-step barrier: next step writes the other LDS buffer, and any
    // wave reaching step s+2 (same buffer) has passed two more barriers than
    // the slowest reader of this buffer.
  }
}

// out[t][o] = bl[o] + sum_k hidden[t][k] * Wl[o][k]
// 64x64 tile, 256 threads, 4x4 micro-tile, BK=16.
__global__ __launch_bounds__(256) void out_gemm_kernel(
    const __hip_bfloat16* __restrict__ hidden, const float* __restrict__ Wl,
    const float* __restrict__ bl, float* __restrict__ out) {
  __shared__ float As[16][68];
  __shared__ float Bs[16][68];
  const int tid = threadIdx.x;
  const int bt = blockIdx.x * 64;
  const int bo = blockIdx.y * 64;
  const int tx = tid & 15;
  const int ty = tid >> 4;
  const int tA = tid >> 2;        // 0..63
  const int kq = (tid & 3) << 2;  // 0,4,8,12
  const unsigned short* hidu = reinterpret_cast<const unsigned short*>(hidden);

  float acc[4][4];
#pragma unroll
  for (int i = 0; i < 4; ++i)
#pragma unroll
    for (int j = 0; j < 4; ++j) acc[i][j] = 0.f;

  for (int k0 = 0; k0 < HID; k0 += 16) {
    const ushort4 av = *reinterpret_cast<const ushort4*>(
        hidu + (size_t)(bt + tA) * HID + k0 + kq);
    As[kq + 0][tA] = __uint_as_float((unsigned)av.x << 16);
    As[kq + 1][tA] = __uint_as_float((unsigned)av.y << 16);
    As[kq + 2][tA] = __uint_as_float((unsigned)av.z << 16);
    As[kq + 3][tA] = __uint_as_float((unsigned)av.w << 16);
    const float4 bv = *reinterpret_cast<const float4*>(
        Wl + (size_t)(bo + tA) * HID + k0 + kq);
    Bs[kq + 0][tA] = bv.x;
    Bs[kq + 1][tA] = bv.y;
    Bs[kq + 2][tA] = bv.z;
    Bs[kq + 3][tA] = bv.w;
    __syncthreads();
#pragma unroll
    for (int k = 0; k < 16; ++k) {
      const float4 a = *reinterpret_cast<const float4*>(&As[k][ty << 2]);
      const float4 bq = *reinterpret_cast<const float4*>(&Bs[k][tx << 2]);
      const float a4[4] = {a.x, a.y, a.z, a.w};
      const float b4[4] = {bq.x, bq.y, bq.z, bq.w};
#pragma unroll
      for (int i = 0; i < 4; ++i)
#pragma unroll
        for (int j = 0; j < 4; ++j) acc[i][j] += a4[i] * b4[j];
    }
    __syncthreads();
  }
#pragma unroll
  for (int i = 0; i < 4; ++i) {
    const int t = bt + (ty << 2) + i;
#pragma unroll
    for (int j = 0; j < 4; ++j) {
      const int o = bo + (tx << 2) + j;
      out[(size_t)t * NOUT + o] = acc[i][j] + bl[o];
    }
  }
}

extern "C" void kernel_launch(void* const* d_in, const int* in_sizes, int n_in,
                              void* d_out, int out_size, void* d_ws,
                              size_t ws_size, hipStream_t stream) {
  (void)in_sizes;
  (void)n_in;
  (void)out_size;
  (void)ws_size;
  // setup_inputs order: ts, ys, wi, wh, b, bn, Wl, bl (all f32)
  const float* ys = (const float*)d_in[1];
  const float* wi = (const float*)d_in[2];
  const float* wh = (const float*)d_in[3];
  const float* b = (const float*)d_in[4];
  const float* bn = (const float*)d_in[5];
  const float* Wl = (const float*)d_in[6];
  const float* bl = (const float*)d_in[7];
  float* out = (float*)d_out;

  u64* h_tag = (u64*)((char*)d_ws + WS_HBUF_OFF);
  __hip_bfloat16* hidden = (__hip_bfloat16*)((char*)d_ws + WS_HIDDEN_OFF);

  gru_init_kernel<<<16, 256, 0, stream>>>(h_tag);

  gru_scan_kernel<<<dim3(256), dim3(256), 0, stream>>>(ys, wi, wh, b, bn,
                                                       hidden, h_tag);

  out_gemm_kernel<<<dim3(T_STEPS / 64, NOUT / 64), 256, 0, stream>>>(
      hidden, Wl, bl, out);
}